// Round 1
// baseline (4323.093 us; speedup 1.0000x reference)
//
#include <hip/hip_runtime.h>
#include <math.h>

#define TT 8
#define BB 32
#define VV 50257
#define DD 256
#define NN 4096
#define HH 4
#define EPS_ 1e-12f

__device__ __forceinline__ float sigf(float x) { return 1.f / (1.f + expf(-x)); }
__device__ __forceinline__ float softplusf_(float x) { return fmaxf(x, 0.f) + log1pf(expf(-fabsf(x))); }

// ---- block reductions (256-thread blocks only) ----
__device__ __forceinline__ float blk_sum(float v, float* s) {
#pragma unroll
  for (int o = 32; o > 0; o >>= 1) v += __shfl_down(v, o);
  __syncthreads();
  if ((threadIdx.x & 63) == 0) s[threadIdx.x >> 6] = v;
  __syncthreads();
  return s[0] + s[1] + s[2] + s[3];
}
__device__ __forceinline__ float blk_max(float v, float* s) {
#pragma unroll
  for (int o = 32; o > 0; o >>= 1) v = fmaxf(v, __shfl_down(v, o));
  __syncthreads();
  if ((threadIdx.x & 63) == 0) s[threadIdx.x >> 6] = v;
  __syncthreads();
  return fmaxf(fmaxf(s[0], s[1]), fmaxf(s[2], s[3]));
}

// ---- init one-hot read/write weights ----
__global__ void init_k(float* rw, float* ww) {
  int i = blockIdx.x * blockDim.x + threadIdx.x;
  if (i < BB) { rw[(size_t)i * NN] = 1.f; ww[(size_t)i * NN] = 1.f; }
}

// ---- x_in = gam*emb + bet + rg*r  (FiLM + read gate fused) ----
__global__ __launch_bounds__(256) void xin_k(
    const int* __restrict__ tokens, const float* __restrict__ embW,
    const float* __restrict__ rgW, const float* __restrict__ rgb,
    const float* __restrict__ filmW, const float* __restrict__ filmb,
    const float* __restrict__ record, const float* __restrict__ rvec,
    float* __restrict__ xout, int t) {
  __shared__ float rec[256];
  int b = blockIdx.x, d = threadIdx.x;
  rec[d] = record[b * 256 + d];
  __syncthreads();
  const float* f1 = filmW + (size_t)d * 256;
  const float* f2 = filmW + (size_t)(256 + d) * 256;
  const float* g1 = rgW + (size_t)d * 256;
  float a1 = 0.f, a2 = 0.f, a3 = 0.f;
  for (int kk = 0; kk < 256; ++kk) {
    float rv = rec[kk];
    a1 += rv * f1[kk]; a2 += rv * f2[kk]; a3 += rv * g1[kk];
  }
  float gam = 1.f + tanhf(a1 + filmb[d]);
  float bet = a2 + filmb[256 + d];
  float rg = sigf(a3 + rgb[d]);
  int tok = tokens[t * BB + b];
  float emb = embW[(size_t)tok * 256 + d];
  xout[b * 256 + d] = gam * emb + bet + rg * rvec[b * 256 + d];
}

// ---- h = ctx + positional encoding ----
__global__ void buildh_k(const float* __restrict__ xin, float* __restrict__ h, int S) {
  int i = blockIdx.x * 256 + threadIdx.x;
  if (i >= S * BB * DD) return;
  int d = i & 255;
  int s = i >> 13;  // BB*DD = 8192 per s
  int si = d >> 1;
  float ang = (float)s * expf(-logf(10000.f) * (float)(2 * si) / 256.f);
  float pe = (d & 1) ? cosf(ang) : sinf(ang);
  h[i] = xin[i] + pe;
}

// ---- generic tiled GEMM: C = act(LN?(A) @ W^T + bias [+resid] [+C]) ----
// A:(M,K) W:(N,K) C:(M,N), 64x64 tile, 4x4 micro, K%16==0
template <int ACT, int RESID, int ACCUM, int LNA>
__global__ __launch_bounds__(256) void gemm_k(
    const float* __restrict__ A, const float* __restrict__ W,
    const float* __restrict__ bias, const float* resid,
    const float* __restrict__ lng, const float* __restrict__ lnb,
    float* C, int M, int N, int K) {
  __shared__ float As[16][68];
  __shared__ float Ws[16][68];
  __shared__ float muS[64], rsS[64];
  __shared__ float red1[64][4], red2[64][4];

  const int tid = threadIdx.x;
  const int tx = tid & 15, ty = tid >> 4;
  const int m0 = blockIdx.y * 64, n0 = blockIdx.x * 64;
  const int ldr = tid >> 2, ldq = (tid & 3) << 2;

  if (LNA) {  // fused row LayerNorm stats over A rows of this tile
    float s1 = 0.f, s2 = 0.f;
    const int q = tid & 3;
    const int m = m0 + ldr;
    if (m < M) {
      const float* ap = A + (size_t)m * K + q * (K >> 2);
      for (int kk = 0; kk < (K >> 2); ++kk) { float a = ap[kk]; s1 += a; s2 += a * a; }
    }
    red1[ldr][q] = s1; red2[ldr][q] = s2;
    __syncthreads();
    if (tid < 64) {
      float su = red1[tid][0] + red1[tid][1] + red1[tid][2] + red1[tid][3];
      float sq = red2[tid][0] + red2[tid][1] + red2[tid][2] + red2[tid][3];
      float mu = su / (float)K;
      float var = fmaxf(sq / (float)K - mu * mu, 0.f);
      muS[tid] = mu;
      rsS[tid] = rsqrtf(var + 1e-5f);
    }
    __syncthreads();
  }

  float acc[4][4] = {};
  for (int kt = 0; kt < K; kt += 16) {
    {
      const int m = m0 + ldr;
      float4 a4 = make_float4(0.f, 0.f, 0.f, 0.f);
      if (m < M) a4 = *(const float4*)(A + (size_t)m * K + kt + ldq);
      if (LNA) {
        const float mu = muS[ldr], rs = rsS[ldr];
        a4.x = (a4.x - mu) * rs * lng[kt + ldq + 0] + lnb[kt + ldq + 0];
        a4.y = (a4.y - mu) * rs * lng[kt + ldq + 1] + lnb[kt + ldq + 1];
        a4.z = (a4.z - mu) * rs * lng[kt + ldq + 2] + lnb[kt + ldq + 2];
        a4.w = (a4.w - mu) * rs * lng[kt + ldq + 3] + lnb[kt + ldq + 3];
      }
      As[ldq + 0][ldr] = a4.x; As[ldq + 1][ldr] = a4.y;
      As[ldq + 2][ldr] = a4.z; As[ldq + 3][ldr] = a4.w;
      const int n = n0 + ldr;
      float4 w4 = make_float4(0.f, 0.f, 0.f, 0.f);
      if (n < N) w4 = *(const float4*)(W + (size_t)n * K + kt + ldq);
      Ws[ldq + 0][ldr] = w4.x; Ws[ldq + 1][ldr] = w4.y;
      Ws[ldq + 2][ldr] = w4.z; Ws[ldq + 3][ldr] = w4.w;
    }
    __syncthreads();
#pragma unroll
    for (int kk = 0; kk < 16; ++kk) {
      const float4 av = *(const float4*)&As[kk][ty << 2];
      const float4 wv = *(const float4*)&Ws[kk][tx << 2];
      acc[0][0] += av.x * wv.x; acc[0][1] += av.x * wv.y; acc[0][2] += av.x * wv.z; acc[0][3] += av.x * wv.w;
      acc[1][0] += av.y * wv.x; acc[1][1] += av.y * wv.y; acc[1][2] += av.y * wv.z; acc[1][3] += av.y * wv.w;
      acc[2][0] += av.z * wv.x; acc[2][1] += av.z * wv.y; acc[2][2] += av.z * wv.z; acc[2][3] += av.z * wv.w;
      acc[3][0] += av.w * wv.x; acc[3][1] += av.w * wv.y; acc[3][2] += av.w * wv.z; acc[3][3] += av.w * wv.w;
    }
    __syncthreads();
  }

#pragma unroll
  for (int i = 0; i < 4; ++i) {
    const int m = m0 + (ty << 2) + i;
    if (m >= M) continue;
#pragma unroll
    for (int j = 0; j < 4; ++j) {
      const int n = n0 + (tx << 2) + j;
      if (n >= N) continue;
      float v = acc[i][j] + bias[n];
      if (RESID) v += resid[(size_t)m * N + n];
      if (ACCUM) v += C[(size_t)m * N + n];
      if (ACT == 1) v = fmaxf(v, 0.f);
      C[(size_t)m * N + n] = v;
    }
  }
}

// ---- small multi-head attention over S<=9 context rows ----
__global__ __launch_bounds__(128) void attn_k(const float* __restrict__ qkv,
                                              float* __restrict__ attnout, int S) {
  int bh = blockIdx.x;
  int b = bh >> 2, h = bh & 3;  // HH=4
  __shared__ float q[9][64], k[9][64], v[9][64], lg[9][12];
  int tid = threadIdx.x;
  for (int i = tid; i < S * 64; i += 128) {
    int s = i >> 6, d = i & 63;
    const float* base = qkv + (size_t)(s * BB + b) * 768 + h * 64 + d;
    q[s][d] = base[0]; k[s][d] = base[256]; v[s][d] = base[512];
  }
  __syncthreads();
  for (int p = tid; p < S * S; p += 128) {
    int s = p / S, t2 = p % S;
    float acc = 0.f;
    for (int d = 0; d < 64; ++d) acc += q[s][d] * k[t2][d];
    lg[s][t2] = acc * 0.125f;  // 1/sqrt(64)
  }
  __syncthreads();
  if (tid < S) {
    float mx = -1e30f;
    for (int t2 = 0; t2 < S; ++t2) mx = fmaxf(mx, lg[tid][t2]);
    float sum = 0.f;
    for (int t2 = 0; t2 < S; ++t2) { float e = expf(lg[tid][t2] - mx); lg[tid][t2] = e; sum += e; }
    float inv = 1.f / sum;
    for (int t2 = 0; t2 < S; ++t2) lg[tid][t2] *= inv;
  }
  __syncthreads();
  for (int i = tid; i < S * 64; i += 128) {
    int s = i >> 6, d = i & 63;
    float o = 0.f;
    for (int t2 = 0; t2 < S; ++t2) o += lg[s][t2] * v[t2][d];
    attnout[(size_t)(s * BB + b) * 256 + h * 64 + d] = o;
  }
}

// ---- standalone LayerNorm over 256-wide rows ----
__global__ __launch_bounds__(256) void ln_k(const float* __restrict__ X,
                                            const float* __restrict__ g,
                                            const float* __restrict__ bta,
                                            float* __restrict__ Y) {
  __shared__ float s8[8];
  int r = blockIdx.x;
  const float* x = X + (size_t)r * 256;
  float v = x[threadIdx.x];
  float mu = blk_sum(v, s8) * (1.f / 256.f);
  float d = v - mu;
  float var = blk_sum(d * d, s8) * (1.f / 256.f);
  float rs = rsqrtf(var + 1e-5f);
  Y[(size_t)r * 256 + threadIdx.x] = d * rs * g[threadIdx.x] + bta[threadIdx.x];
}

// ---- LSTM pointwise ----
__global__ __launch_bounds__(256) void lstmpw_k(const float* __restrict__ gates,
                                                float* cxp, float* hxp, float* xlp,
                                                const float* __restrict__ coutp,
                                                float* cfinp, float* recp, int last) {
  int b = blockIdx.x, d = threadIdx.x;
  const float* g = gates + (size_t)b * 1024;
  float ig = sigf(g[d]), fg = sigf(g[256 + d]), gg = tanhf(g[512 + d]), og = sigf(g[768 + d]);
  float c = fg * cxp[b * 256 + d] + ig * gg;
  float hN = og * tanhf(c);
  cxp[b * 256 + d] = c;
  hxp[b * 256 + d] = hN;
  xlp[b * 256 + d] = hN;
  if (last) {
    recp[b * 256 + d] = hN;
    cfinp[b * 256 + d] = coutp[b * 256 + d] + hN;
  }
}

// ---- pass A: per-row dot(key_r), dot(key_w), ||row||^2 over memory ----
__global__ __launch_bounds__(256) void passA_k(const float* __restrict__ mem,
                                               const float* __restrict__ rp,
                                               const float* __restrict__ wp,
                                               float* __restrict__ dr,
                                               float* __restrict__ dw,
                                               float* __restrict__ nrm) {
  __shared__ float kr[256], kw[256];
  int b = blockIdx.y;
  int tid = threadIdx.x;
  kr[tid] = rp[(size_t)b * 262 + tid];
  kw[tid] = wp[(size_t)b * 774 + tid];
  __syncthreads();
  int w = tid >> 6, lane = tid & 63;
  float4 kr4 = *(float4*)&kr[lane * 4];
  float4 kw4 = *(float4*)&kw[lane * 4];
  int n0 = blockIdx.x * 16 + w * 4;
  for (int rr = 0; rr < 4; ++rr) {
    int n = n0 + rr;
    const float4* row = (const float4*)(mem + ((size_t)b * NN + n) * 256);
    float4 m4 = row[lane];
    float pr = m4.x * kr4.x + m4.y * kr4.y + m4.z * kr4.z + m4.w * kr4.w;
    float pw = m4.x * kw4.x + m4.y * kw4.y + m4.z * kw4.z + m4.w * kw4.w;
    float pn = m4.x * m4.x + m4.y * m4.y + m4.z * m4.z + m4.w * m4.w;
#pragma unroll
    for (int o = 32; o > 0; o >>= 1) {
      pr += __shfl_down(pr, o); pw += __shfl_down(pw, o); pn += __shfl_down(pn, o);
    }
    if (lane == 0) {
      dr[(size_t)b * NN + n] = pr;
      dw[(size_t)b * NN + n] = pw;
      nrm[(size_t)b * NN + n] = pn;
    }
  }
}

// ---- addressing: cos->softmax->gate->shift->sharpen->normalize (one block per (b,head)) ----
__global__ __launch_bounds__(256) void addr_k(const float* __restrict__ dr,
                                              const float* __restrict__ dw,
                                              const float* __restrict__ nrm,
                                              const float* __restrict__ rp,
                                              const float* __restrict__ wp,
                                              float* rw, float* ww,
                                              float* __restrict__ ea,
                                              float* __restrict__ rvec) {
  __shared__ float wg[4096];
  __shared__ float s8[8];
  int head = blockIdx.x & 1, b = blockIdx.x >> 1;
  int tid = threadIdx.x;
  const float* p = head ? wp + (size_t)b * 774 : rp + (size_t)b * 262;
  const float* dot = (head ? dw : dr) + (size_t)b * NN;
  const float* n2 = nrm + (size_t)b * NN;
  float* wout = (head ? ww : rw) + (size_t)b * NN;

  float kv = p[tid];
  float kn = sqrtf(blk_sum(kv * kv, s8)) + EPS_;
  float beta = p[256], gate = p[257], sh0 = p[258], sh1 = p[259], sh2 = p[260], gamma = p[261];
  float spb = softplusf_(beta);
  float g = sigf(gate);
  float mx3 = fmaxf(sh0, fmaxf(sh1, sh2));
  float e0 = expf(sh0 - mx3), e1 = expf(sh1 - mx3), e2 = expf(sh2 - mx3);
  float esum = e0 + e1 + e2;
  float s0 = e0 / esum, s1 = e1 / esum, s2 = e2 / esum;
  float gp = 1.f + softplusf_(gamma);

  float l[16];
  float lmax = -1e30f;
#pragma unroll
  for (int i = 0; i < 16; ++i) {
    int n = tid + i * 256;
    float cs = dot[n] / ((sqrtf(n2[n]) + EPS_) * kn);
    l[i] = spb * cs;
    lmax = fmaxf(lmax, l[i]);
  }
  float Mx = blk_max(lmax, s8);
  float es = 0.f;
#pragma unroll
  for (int i = 0; i < 16; ++i) { l[i] = expf(l[i] - Mx); es += l[i]; }
  float SS = blk_sum(es, s8);
  float inv = 1.f / SS;
#pragma unroll
  for (int i = 0; i < 16; ++i) {
    int n = tid + i * 256;
    wg[n] = g * l[i] * inv + (1.f - g) * wout[n];
  }
  __syncthreads();
  float wt[16];
  float wsum = 0.f;
#pragma unroll
  for (int i = 0; i < 16; ++i) {
    int n = tid + i * 256;
    float sh = s0 * wg[(n + 1) & 4095] + s1 * wg[n] + s2 * wg[(n + 4095) & 4095];
    wt[i] = powf(sh + EPS_, gp);
    wsum += wt[i];
  }
  float WS = blk_sum(wsum, s8) + EPS_;
  float winv = 1.f / WS;
#pragma unroll
  for (int i = 0; i < 16; ++i) wout[tid + i * 256] = wt[i] * winv;

  if (head) {
    ea[(size_t)b * 512 + tid] = sigf(p[262 + tid]);
    ea[(size_t)b * 512 + 256 + tid] = tanhf(p[518 + tid]);
  } else {
    rvec[(size_t)b * 256 + tid] = 0.f;  // zero r accumulator for pass B
  }
}

// ---- pass B: memory erase/add update + fused r = read_w_new . memory_new ----
__global__ __launch_bounds__(256) void passB_k(float* mem, const float* __restrict__ ww,
                                               const float* __restrict__ rw,
                                               const float* __restrict__ ea,
                                               float* __restrict__ rvec) {
  __shared__ float eS[256], aS[256];
  __shared__ float rred[4][256];
  int b = blockIdx.y, tid = threadIdx.x;
  eS[tid] = ea[(size_t)b * 512 + tid];
  aS[tid] = ea[(size_t)b * 512 + 256 + tid];
  __syncthreads();
  int w = tid >> 6, lane = tid & 63;
  float4 e4 = *(float4*)&eS[lane * 4];
  float4 a4 = *(float4*)&aS[lane * 4];
  float4 racc = make_float4(0.f, 0.f, 0.f, 0.f);
  int n0 = blockIdx.x * 128 + w * 32;
  for (int rr = 0; rr < 32; ++rr) {
    int n = n0 + rr;
    float wt = ww[(size_t)b * NN + n];
    float rwv = rw[(size_t)b * NN + n];
    float4* row = (float4*)(mem + ((size_t)b * NN + n) * 256);
    float4 m = row[lane];
    m.x = m.x * (1.f - wt * e4.x) + wt * a4.x;
    m.y = m.y * (1.f - wt * e4.y) + wt * a4.y;
    m.z = m.z * (1.f - wt * e4.z) + wt * a4.z;
    m.w = m.w * (1.f - wt * e4.w) + wt * a4.w;
    row[lane] = m;
    racc.x += rwv * m.x; racc.y += rwv * m.y; racc.z += rwv * m.z; racc.w += rwv * m.w;
  }
  rred[w][lane * 4 + 0] = racc.x;
  rred[w][lane * 4 + 1] = racc.y;
  rred[w][lane * 4 + 2] = racc.z;
  rred[w][lane * 4 + 3] = racc.w;
  __syncthreads();
  float s = rred[0][tid] + rred[1][tid] + rred[2][tid] + rred[3][tid];
  atomicAdd(rvec + (size_t)b * 256 + tid, s);
}

extern "C" void kernel_launch(void* const* d_in, const int* in_sizes, int n_in,
                              void* d_out, int out_size, void* d_ws, size_t ws_size,
                              hipStream_t stream) {
  const int* tokens = (const int*)d_in[0];
  const float* emb_W = (const float*)d_in[1];
  const float* read_gate_W = (const float*)d_in[2];
  const float* read_gate_b = (const float*)d_in[3];
  const float* film_W = (const float*)d_in[4];
  const float* film_b = (const float*)d_in[5];
  const float* t_Wqkv = (const float*)d_in[6];
  const float* t_bqkv = (const float*)d_in[7];
  const float* t_Wo = (const float*)d_in[8];
  const float* t_bo = (const float*)d_in[9];
  const float* t_ln1_g = (const float*)d_in[10];
  const float* t_ln1_b = (const float*)d_in[11];
  const float* t_ln2_g = (const float*)d_in[12];
  const float* t_ln2_b = (const float*)d_in[13];
  const float* t_W1 = (const float*)d_in[14];
  const float* t_b1 = (const float*)d_in[15];
  const float* t_W2 = (const float*)d_in[16];
  const float* t_b2 = (const float*)d_in[17];
  const float* out_ln_g = (const float*)d_in[18];
  const float* out_ln_b = (const float*)d_in[19];
  const float* lstm_Wih = (const float*)d_in[20];
  const float* lstm_Whh = (const float*)d_in[21];
  const float* lstm_bih = (const float*)d_in[22];
  const float* lstm_bhh = (const float*)d_in[23];
  const float* head_W = (const float*)d_in[24];
  const float* head_b = (const float*)d_in[25];
  const float* read_W = (const float*)d_in[26];
  const float* read_b = (const float*)d_in[27];
  const float* write_W = (const float*)d_in[28];
  const float* write_b = (const float*)d_in[29];
  float* out = (float*)d_out;

  float* ws = (float*)d_ws;
  size_t off = 0;
  float* memory = ws + off; off += (size_t)BB * NN * DD;
  float* read_w = ws + off; off += (size_t)BB * NN;
  float* write_w = ws + off; off += (size_t)BB * NN;
  float* record = ws + off; off += BB * DD;
  float* hx = ws + off; off += 2 * BB * DD;
  float* cx = ws + off; off += 2 * BB * DD;
  float* r_vec = ws + off; off += BB * DD;
  float* xin_all = ws + off; off += 9 * BB * DD;
  float* dot_r = ws + off; off += (size_t)BB * NN;
  float* dot_w = ws + off; off += (size_t)BB * NN;
  float* norm2 = ws + off; off += (size_t)BB * NN;
  size_t zero_floats = off;  // everything above starts zeroed
  float* h = ws + off; off += 9 * BB * DD;
  float* qkv = ws + off; off += 9 * BB * 3 * DD;
  float* attnout = ws + off; off += 9 * BB * DD;
  float* mid = ws + off; off += 9 * BB * 4 * DD;
  float* c_out = ws + off; off += BB * DD;
  float* c_fin = ws + off; off += BB * DD;
  float* xl = ws + off; off += BB * DD;
  float* gates = ws + off; off += BB * 4 * DD;
  float* rp = ws + off; off += BB * 262;
  float* wp = ws + off; off += BB * 774;
  float* erase_add = ws + off; off += BB * 2 * DD;
  if (ws_size < off * sizeof(float)) return;  // workspace too small (should not happen)

  (void)hipMemsetAsync(ws, 0, zero_floats * sizeof(float), stream);
  init_k<<<1, 64, 0, stream>>>(read_w, write_w);

  auto g2 = [](int n, int m) { return dim3((unsigned)((n + 63) / 64), (unsigned)((m + 63) / 64)); };

  for (int t = 0; t < TT; ++t) {
    const int S = t + 2;       // ctx rows: [zeros, x_0..x_t]
    const int M = S * BB;

    xin_k<<<BB, 256, 0, stream>>>(tokens, emb_W, read_gate_W, read_gate_b, film_W, film_b,
                                  record, r_vec, xin_all + (size_t)(t + 1) * BB * DD, t);
    buildh_k<<<S * 32, 256, 0, stream>>>(xin_all, h, S);

    for (int l = 0; l < 2; ++l) {
      const float* Wqkv = t_Wqkv + (size_t)l * 768 * 256;
      const float* bqkv = t_bqkv + (size_t)l * 768;
      const float* Wo = t_Wo + (size_t)l * 256 * 256;
      const float* bo = t_bo + (size_t)l * 256;
      const float* ln1g = t_ln1_g + (size_t)l * 256;
      const float* ln1b = t_ln1_b + (size_t)l * 256;
      const float* ln2g = t_ln2_g + (size_t)l * 256;
      const float* ln2b = t_ln2_b + (size_t)l * 256;
      const float* W1 = t_W1 + (size_t)l * 1024 * 256;
      const float* b1 = t_b1 + (size_t)l * 1024;
      const float* W2 = t_W2 + (size_t)l * 256 * 1024;
      const float* b2 = t_b2 + (size_t)l * 256;

      gemm_k<0, 0, 0, 1><<<g2(768, M), 256, 0, stream>>>(h, Wqkv, bqkv, nullptr, ln1g, ln1b, qkv, M, 768, 256);
      attn_k<<<BB * HH, 128, 0, stream>>>(qkv, attnout, S);
      gemm_k<0, 1, 0, 0><<<g2(256, M), 256, 0, stream>>>(attnout, Wo, bo, h, nullptr, nullptr, h, M, 256, 256);
      gemm_k<1, 0, 0, 1><<<g2(1024, M), 256, 0, stream>>>(h, W1, b1, nullptr, ln2g, ln2b, mid, M, 1024, 256);
      gemm_k<0, 1, 0, 0><<<g2(256, M), 256, 0, stream>>>(mid, W2, b2, h, nullptr, nullptr, h, M, 256, 1024);
    }

    ln_k<<<BB, 256, 0, stream>>>(h + (size_t)(S - 1) * BB * DD, out_ln_g, out_ln_b, c_out);

    const float* xlp = c_out;
    for (int l = 0; l < 2; ++l) {
      const float* Wih = lstm_Wih + (size_t)l * 1024 * 256;
      const float* Whh = lstm_Whh + (size_t)l * 1024 * 256;
      const float* bih = lstm_bih + (size_t)l * 1024;
      const float* bhh = lstm_bhh + (size_t)l * 1024;
      gemm_k<0, 0, 0, 0><<<g2(1024, BB), 256, 0, stream>>>(xlp, Wih, bih, nullptr, nullptr, nullptr, gates, BB, 1024, 256);
      gemm_k<0, 0, 1, 0><<<g2(1024, BB), 256, 0, stream>>>(hx + (size_t)l * BB * DD, Whh, bhh, nullptr, nullptr, nullptr, gates, BB, 1024, 256);
      lstmpw_k<<<BB, 256, 0, stream>>>(gates, cx + (size_t)l * BB * DD, hx + (size_t)l * BB * DD,
                                       xl, c_out, c_fin, record, l == 1);
      xlp = xl;
    }

    gemm_k<0, 0, 0, 0><<<g2(VV, BB), 256, 0, stream>>>(c_fin, head_W, head_b, nullptr, nullptr, nullptr,
                                                       out + (size_t)t * BB * VV, BB, VV, 256);

    if (t < TT - 1) {  // final-step addressing/memory update never affects logits
      gemm_k<0, 0, 0, 0><<<g2(262, BB), 256, 0, stream>>>(c_fin, read_W, read_b, nullptr, nullptr, nullptr, rp, BB, 262, 256);
      gemm_k<0, 0, 0, 0><<<g2(774, BB), 256, 0, stream>>>(c_fin, write_W, write_b, nullptr, nullptr, nullptr, wp, BB, 774, 256);
      if (t > 0)  // at t==0 memory is all zeros; dot_r/dot_w/norm2 are zero-initialized
        passA_k<<<dim3(NN / 16, BB), 256, 0, stream>>>(memory, rp, wp, dot_r, dot_w, norm2);
      addr_k<<<2 * BB, 256, 0, stream>>>(dot_r, dot_w, norm2, rp, wp, read_w, write_w, erase_add, r_vec);
      passB_k<<<dim3(NN / 128, BB), 256, 0, stream>>>(memory, write_w, read_w, erase_add, r_vec);
    }
  }
}

// Round 2
// 2688.652 us; speedup vs baseline: 1.6079x; 1.6079x over previous
//
#include <hip/hip_runtime.h>
#include <math.h>

#define TT 8
#define BB 32
#define VV 50257
#define DD 256
#define NN 4096
#define HH 4
#define EPS_ 1e-12f

typedef __attribute__((ext_vector_type(8))) short short8;
typedef __attribute__((ext_vector_type(4))) float f32x4;

__device__ __forceinline__ float sigf(float x) { return 1.f / (1.f + expf(-x)); }
__device__ __forceinline__ float softplusf_(float x) { return fmaxf(x, 0.f) + log1pf(expf(-fabsf(x))); }
__device__ __forceinline__ unsigned short f2bf(float f) {
  union { float f; unsigned u; } c; c.f = f;
  return (unsigned short)((c.u + 0x7FFFu + ((c.u >> 16) & 1u)) >> 16);
}

// ---- block reductions (256-thread blocks only) ----
__device__ __forceinline__ float blk_sum(float v, float* s) {
#pragma unroll
  for (int o = 32; o > 0; o >>= 1) v += __shfl_down(v, o);
  __syncthreads();
  if ((threadIdx.x & 63) == 0) s[threadIdx.x >> 6] = v;
  __syncthreads();
  return s[0] + s[1] + s[2] + s[3];
}
__device__ __forceinline__ float blk_max(float v, float* s) {
#pragma unroll
  for (int o = 32; o > 0; o >>= 1) v = fmaxf(v, __shfl_down(v, o));
  __syncthreads();
  if ((threadIdx.x & 63) == 0) s[threadIdx.x >> 6] = v;
  __syncthreads();
  return fmaxf(fmaxf(s[0], s[1]), fmaxf(s[2], s[3]));
}

// ---- one-time init: one-hot weights + hpe row 0 (zeros + pe[0]) ----
__global__ void init_k(float* rw, float* ww, float* hpe) {
  int i = blockIdx.x * 256 + threadIdx.x;
  if (i < BB) { rw[(size_t)i * NN] = 1.f; ww[(size_t)i * NN] = 1.f; }
  if (i < BB * DD) hpe[i] = (i & 1) ? 1.f : 0.f;  // sin(0)=0 even dims, cos(0)=1 odd dims
}

// ---- head_W f32 -> bf16 ----
__global__ void cvtw_k(const float* __restrict__ W, unsigned short* __restrict__ Wh, int n4) {
  int i = blockIdx.x * 256 + threadIdx.x;
  if (i >= n4) return;
  float4 v = *(const float4*)(W + (size_t)i * 4);
  unsigned u0 = (unsigned)f2bf(v.x) | ((unsigned)f2bf(v.y) << 16);
  unsigned u1 = (unsigned)f2bf(v.z) | ((unsigned)f2bf(v.w) << 16);
  uint2 p; p.x = u0; p.y = u1;
  *(uint2*)(Wh + (size_t)i * 4) = p;
}

// ---- build combined LSTM weights [Wih|Whh] (2 x 1024 x 512) + bias ----
__global__ void catlstm_k(const float* __restrict__ Wih, const float* __restrict__ Whh,
                          const float* __restrict__ bih, const float* __restrict__ bhh,
                          float* __restrict__ Wc, float* __restrict__ cb) {
  int i = blockIdx.x * 256 + threadIdx.x;
  if (i >= 2 * 1024 * 512) return;
  int k = i & 511, n = (i >> 9) & 1023, l = i >> 19;
  Wc[i] = (k < 256) ? Wih[((size_t)l * 1024 + n) * 256 + k] : Whh[((size_t)l * 1024 + n) * 256 + (k - 256)];
  if (k == 0) cb[l * 1024 + n] = bih[l * 1024 + n] + bhh[l * 1024 + n];
}

// ---- build combined read/write param weights (1036 x 256) + bias ----
__global__ void catrw_k(const float* __restrict__ rW, const float* __restrict__ rb,
                        const float* __restrict__ wW, const float* __restrict__ wb,
                        float* __restrict__ Wrw, float* __restrict__ brw) {
  int i = blockIdx.x * 256 + threadIdx.x;
  if (i >= 1036 * 256) return;
  int k = i & 255, n = i >> 8;
  Wrw[i] = (n < 262) ? rW[(size_t)n * 256 + k] : wW[(size_t)(n - 262) * 256 + k];
  if (k == 0) brw[n] = (n < 262) ? rb[n] : wb[n - 262];
}

// ---- x_in = gam*emb + bet + rg*r, + positional enc, written into hpe row t+1 ----
__global__ __launch_bounds__(256) void xin_k(
    const int* __restrict__ tokens, const float* __restrict__ embW,
    const float* __restrict__ rgW, const float* __restrict__ rgb,
    const float* __restrict__ filmW, const float* __restrict__ filmb,
    const float* __restrict__ record, const float* __restrict__ rvec,
    float* __restrict__ hpe, int t) {
  __shared__ float rec[256];
  int b = blockIdx.x, d = threadIdx.x;
  rec[d] = record[b * 256 + d];
  __syncthreads();
  const float* f1 = filmW + (size_t)d * 256;
  const float* f2 = filmW + (size_t)(256 + d) * 256;
  const float* g1 = rgW + (size_t)d * 256;
  float a1 = 0.f, a2 = 0.f, a3 = 0.f;
  for (int kk = 0; kk < 256; ++kk) {
    float rv = rec[kk];
    a1 += rv * f1[kk]; a2 += rv * f2[kk]; a3 += rv * g1[kk];
  }
  float gam = 1.f + tanhf(a1 + filmb[d]);
  float bet = a2 + filmb[256 + d];
  float rg = sigf(a3 + rgb[d]);
  int tok = tokens[t * BB + b];
  float emb = embW[(size_t)tok * 256 + d];
  float ang = (float)(t + 1) * expf(-logf(10000.f) * (float)(d & ~1) / 256.f);
  float pe = (d & 1) ? cosf(ang) : sinf(ang);
  hpe[((size_t)(t + 1) * BB + b) * 256 + d] = gam * emb + bet + rg * rvec[b * 256 + d] + pe;
}

// ---- tiled GEMM, double-buffered, C = act(LN?(A) @ W^T + bias [+resid]) ----
// A:(M,K) W:(N,K) C:(M,N). Tile TM x TN, 256 threads, micro (TM/16)x(TN/16).
template <int TM, int TN, int ACT, int RESID, int LNA>
__global__ __launch_bounds__(256) void gemm_k(
    const float* __restrict__ A, const float* __restrict__ W,
    const float* __restrict__ bias, const float* resid,
    const float* __restrict__ lng, const float* __restrict__ lnb,
    float* C, int M, int N, int K) {
  constexpr int RM = TM / 16, RN = TN / 16;
  __shared__ float As[2][16][TM + 4];
  __shared__ float Ws[2][16][TN + 4];
  __shared__ float muS[TM], rsS[TM];
  const int tid = threadIdx.x;
  const int tx = tid & 15, ty = tid >> 4;
  const int m0 = blockIdx.y * TM, n0 = blockIdx.x * TN;
  const int lar = tid >> 2;
  const int laq = (tid & 3) << 2;

  if constexpr (LNA) {
    __shared__ float red1[TM][4], red2[TM][4];
    if (tid < TM * 4) {
      const int q = tid & 3, m = m0 + lar;
      float s1 = 0.f, s2 = 0.f;
      if (m < M) {
        const float* ap = A + (size_t)m * K + q * (K >> 2);
        for (int kk = 0; kk < (K >> 2); ++kk) { float a = ap[kk]; s1 += a; s2 += a * a; }
      }
      red1[lar][q] = s1; red2[lar][q] = s2;
    }
    __syncthreads();
    if (tid < TM) {
      float su = red1[tid][0] + red1[tid][1] + red1[tid][2] + red1[tid][3];
      float sq = red2[tid][0] + red2[tid][1] + red2[tid][2] + red2[tid][3];
      float mu = su / (float)K;
      float var = fmaxf(sq / (float)K - mu * mu, 0.f);
      muS[tid] = mu; rsS[tid] = rsqrtf(var + 1e-5f);
    }
    __syncthreads();
  }

  const int KT = K >> 4;
  float4 a4 = make_float4(0.f, 0.f, 0.f, 0.f), w4 = make_float4(0.f, 0.f, 0.f, 0.f);
  if (tid < TM * 4) {
    const int m = m0 + lar;
    if (m < M) {
      a4 = *(const float4*)(A + (size_t)m * K + laq);
      if constexpr (LNA) {
        const float mu = muS[lar], rs = rsS[lar];
        a4.x = (a4.x - mu) * rs * lng[laq + 0] + lnb[laq + 0];
        a4.y = (a4.y - mu) * rs * lng[laq + 1] + lnb[laq + 1];
        a4.z = (a4.z - mu) * rs * lng[laq + 2] + lnb[laq + 2];
        a4.w = (a4.w - mu) * rs * lng[laq + 3] + lnb[laq + 3];
      }
    }
  }
  if (tid < TN * 4) {
    const int nn = n0 + lar;
    if (nn < N) w4 = *(const float4*)(W + (size_t)nn * K + laq);
  }

  float acc[RM][RN] = {};
  int buf = 0;
  for (int kt = 0; kt < KT; ++kt) {
    if (tid < TM * 4) {
      As[buf][laq + 0][lar] = a4.x; As[buf][laq + 1][lar] = a4.y;
      As[buf][laq + 2][lar] = a4.z; As[buf][laq + 3][lar] = a4.w;
    }
    if (tid < TN * 4) {
      Ws[buf][laq + 0][lar] = w4.x; Ws[buf][laq + 1][lar] = w4.y;
      Ws[buf][laq + 2][lar] = w4.z; Ws[buf][laq + 3][lar] = w4.w;
    }
    __syncthreads();
    if (kt + 1 < KT) {
      const int k1 = (kt + 1) << 4;
      a4 = make_float4(0.f, 0.f, 0.f, 0.f); w4 = make_float4(0.f, 0.f, 0.f, 0.f);
      if (tid < TM * 4) {
        const int m = m0 + lar;
        if (m < M) {
          a4 = *(const float4*)(A + (size_t)m * K + k1 + laq);
          if constexpr (LNA) {
            const float mu = muS[lar], rs = rsS[lar];
            a4.x = (a4.x - mu) * rs * lng[k1 + laq + 0] + lnb[k1 + laq + 0];
            a4.y = (a4.y - mu) * rs * lng[k1 + laq + 1] + lnb[k1 + laq + 1];
            a4.z = (a4.z - mu) * rs * lng[k1 + laq + 2] + lnb[k1 + laq + 2];
            a4.w = (a4.w - mu) * rs * lng[k1 + laq + 3] + lnb[k1 + laq + 3];
          }
        }
      }
      if (tid < TN * 4) {
        const int nn = n0 + lar;
        if (nn < N) w4 = *(const float4*)(W + (size_t)nn * K + k1 + laq);
      }
    }
#pragma unroll
    for (int kk = 0; kk < 16; ++kk) {
      float av[RM], wv[RN];
      if constexpr (RM == 4) {
        float4 tv = *(const float4*)&As[buf][kk][ty << 2];
        av[0] = tv.x; av[1] = tv.y; av[2] = tv.z; av[3] = tv.w;
      } else {
        float2 tv = *(const float2*)&As[buf][kk][ty << 1];
        av[0] = tv.x; av[1] = tv.y;
      }
      if constexpr (RN == 4) {
        float4 tv = *(const float4*)&Ws[buf][kk][tx << 2];
        wv[0] = tv.x; wv[1] = tv.y; wv[2] = tv.z; wv[3] = tv.w;
      } else {
        float2 tv = *(const float2*)&Ws[buf][kk][tx << 1];
        wv[0] = tv.x; wv[1] = tv.y;
      }
#pragma unroll
      for (int i = 0; i < RM; ++i)
#pragma unroll
        for (int j = 0; j < RN; ++j) acc[i][j] += av[i] * wv[j];
    }
    buf ^= 1;
  }

#pragma unroll
  for (int i = 0; i < RM; ++i) {
    const int m = m0 + ty * RM + i;
    if (m >= M) continue;
#pragma unroll
    for (int j = 0; j < RN; ++j) {
      const int n = n0 + tx * RN + j;
      if (n >= N) continue;
      float v = acc[i][j] + bias[n];
      if constexpr (RESID) v += resid[(size_t)m * N + n];
      if constexpr (ACT) v = fmaxf(v, 0.f);
      C[(size_t)m * N + n] = v;
    }
  }
}

// ---- full multi-head attention over S<=9 rows (layer 1) ----
__global__ __launch_bounds__(128) void attn_k(const float* __restrict__ qkv,
                                              float* __restrict__ attnout, int S) {
  int bh = blockIdx.x;
  int b = bh >> 2, h = bh & 3;
  __shared__ float q[9][64], k[9][64], v[9][64], lg[9][12];
  int tid = threadIdx.x;
  for (int i = tid; i < S * 64; i += 128) {
    int s = i >> 6, d = i & 63;
    const float* base = qkv + (size_t)(s * BB + b) * 768 + h * 64 + d;
    q[s][d] = base[0]; k[s][d] = base[256]; v[s][d] = base[512];
  }
  __syncthreads();
  for (int p = tid; p < S * S; p += 128) {
    int s = p / S, t2 = p % S;
    float acc = 0.f;
    for (int d = 0; d < 64; ++d) acc += q[s][d] * k[t2][d];
    lg[s][t2] = acc * 0.125f;
  }
  __syncthreads();
  if (tid < S) {
    float mx = -1e30f;
    for (int t2 = 0; t2 < S; ++t2) mx = fmaxf(mx, lg[tid][t2]);
    float sum = 0.f;
    for (int t2 = 0; t2 < S; ++t2) { float e = expf(lg[tid][t2] - mx); lg[tid][t2] = e; sum += e; }
    float inv = 1.f / sum;
    for (int t2 = 0; t2 < S; ++t2) lg[tid][t2] *= inv;
  }
  __syncthreads();
  for (int i = tid; i < S * 64; i += 128) {
    int s = i >> 6, d = i & 63;
    float o = 0.f;
    for (int t2 = 0; t2 < S; ++t2) o += lg[s][t2] * v[t2][d];
    attnout[(size_t)(s * BB + b) * 256 + h * 64 + d] = o;
  }
}

// ---- last-row-only attention (layer 2): one 64-thread block per (b,h) ----
__global__ __launch_bounds__(64) void attnl_k(const float* __restrict__ qkv,
                                              float* __restrict__ aout, int S) {
  int bh = blockIdx.x;
  int b = bh >> 2, h = bh & 3;
  int d = threadIdx.x;
  __shared__ float sc[9];
  float qd = qkv[(size_t)((S - 1) * BB + b) * 768 + h * 64 + d];
  for (int j = 0; j < S; ++j) {
    float p = qd * qkv[(size_t)(j * BB + b) * 768 + h * 64 + 256 + d];
#pragma unroll
    for (int o = 32; o > 0; o >>= 1) p += __shfl_down(p, o);
    if (d == 0) sc[j] = p * 0.125f;
  }
  __syncthreads();
  float mx = -1e30f;
  for (int j = 0; j < S; ++j) mx = fmaxf(mx, sc[j]);
  float pj[9], sum = 0.f;
  for (int j = 0; j < S; ++j) { pj[j] = expf(sc[j] - mx); sum += pj[j]; }
  float inv = 1.f / sum;
  float o = 0.f;
  for (int j = 0; j < S; ++j) o += pj[j] * inv * qkv[(size_t)(j * BB + b) * 768 + h * 64 + 512 + d];
  aout[(size_t)b * 256 + h * 64 + d] = o;
}

// ---- LayerNorm over 256-wide rows; writes c_out and lstm_in0 x-part ----
__global__ __launch_bounds__(256) void ln_k(const float* __restrict__ X,
                                            const float* __restrict__ g,
                                            const float* __restrict__ bta,
                                            float* __restrict__ Y, float* __restrict__ li0) {
  __shared__ float s8[8];
  int r = blockIdx.x;
  const float* x = X + (size_t)r * 256;
  float v = x[threadIdx.x];
  float mu = blk_sum(v, s8) * (1.f / 256.f);
  float d = v - mu;
  float var = blk_sum(d * d, s8) * (1.f / 256.f);
  float rs = rsqrtf(var + 1e-5f);
  float y = d * rs * g[threadIdx.x] + bta[threadIdx.x];
  Y[(size_t)r * 256 + threadIdx.x] = y;
  li0[(size_t)r * 512 + threadIdx.x] = y;
}

// ---- LSTM pointwise ----
__global__ __launch_bounds__(256) void lstmpw_k(const float* __restrict__ gates,
                                                float* cxp, float* li_l, float* li_next,
                                                const float* __restrict__ coutp,
                                                float* cfinp, unsigned short* cfb,
                                                float* recp, int last) {
  int b = blockIdx.x, d = threadIdx.x;
  const float* g = gates + (size_t)b * 1024;
  float ig = sigf(g[d]), fg = sigf(g[256 + d]), gg = tanhf(g[512 + d]), og = sigf(g[768 + d]);
  float c = fg * cxp[b * 256 + d] + ig * gg;
  float hN = og * tanhf(c);
  cxp[b * 256 + d] = c;
  li_l[(size_t)b * 512 + 256 + d] = hN;  // hx for next step's same-layer gemm
  if (last) {
    recp[b * 256 + d] = hN;
    float cf = coutp[b * 256 + d] + hN;
    cfinp[b * 256 + d] = cf;
    cfb[b * 256 + d] = f2bf(cf);
  } else {
    li_next[(size_t)b * 512 + d] = hN;
  }
}

// ---- head: logits = c_fin(bf16) @ head_W(bf16)^T + head_b via MFMA ----
__global__ __launch_bounds__(256) void head_k(const unsigned short* __restrict__ Wh,
                                              const unsigned short* __restrict__ Ah,
                                              const float* __restrict__ hb,
                                              float* __restrict__ out) {
  const int tid = threadIdx.x;
  const int w = tid >> 6, l = tid & 63;
  const int r = l & 15, q = l >> 4;
  const int n = blockIdx.x * 64 + w * 16 + r;
  const int nc = n < VV ? n : VV - 1;
  const short* Ap = (const short*)Ah;
  const short* Wp = (const short*)Wh + (size_t)nc * 256;
  short8 a0[8], a1[8], bf[8];
#pragma unroll
  for (int kt = 0; kt < 8; ++kt) {
    a0[kt] = *(const short8*)(Ap + r * 256 + kt * 32 + q * 8);
    a1[kt] = *(const short8*)(Ap + (16 + r) * 256 + kt * 32 + q * 8);
    bf[kt] = *(const short8*)(Wp + kt * 32 + q * 8);
  }
  f32x4 acc0 = {0.f, 0.f, 0.f, 0.f}, acc1 = {0.f, 0.f, 0.f, 0.f};
#pragma unroll
  for (int kt = 0; kt < 8; ++kt) {
    acc0 = __builtin_amdgcn_mfma_f32_16x16x32_bf16(a0[kt], bf[kt], acc0, 0, 0, 0);
    acc1 = __builtin_amdgcn_mfma_f32_16x16x32_bf16(a1[kt], bf[kt], acc1, 0, 0, 0);
  }
  if (n < VV) {
    float bb = hb[n];
#pragma unroll
    for (int e = 0; e < 4; ++e) {
      int m = q * 4 + e;
      out[(size_t)m * VV + n] = acc0[e] + bb;
      out[(size_t)(16 + m) * VV + n] = acc1[e] + bb;
    }
  }
}

// ---- pass A: per-row dot(key_r), dot(key_w), ||row||^2 over memory ----
__global__ __launch_bounds__(256) void passA_k(const float* __restrict__ mem,
                                               const float* __restrict__ rpwp,
                                               float* __restrict__ dr,
                                               float* __restrict__ dw,
                                               float* __restrict__ nrm) {
  __shared__ float kr[256], kw[256];
  int b = blockIdx.y;
  int tid = threadIdx.x;
  kr[tid] = rpwp[(size_t)b * 1036 + tid];
  kw[tid] = rpwp[(size_t)b * 1036 + 262 + tid];
  __syncthreads();
  int w = tid >> 6, lane = tid & 63;
  float4 kr4 = *(float4*)&kr[lane * 4];
  float4 kw4 = *(float4*)&kw[lane * 4];
  int n0 = blockIdx.x * 16 + w * 4;
  for (int rr = 0; rr < 4; ++rr) {
    int n = n0 + rr;
    const float4* row = (const float4*)(mem + ((size_t)b * NN + n) * 256);
    float4 m4 = row[lane];
    float pr = m4.x * kr4.x + m4.y * kr4.y + m4.z * kr4.z + m4.w * kr4.w;
    float pw = m4.x * kw4.x + m4.y * kw4.y + m4.z * kw4.z + m4.w * kw4.w;
    float pn = m4.x * m4.x + m4.y * m4.y + m4.z * m4.z + m4.w * m4.w;
#pragma unroll
    for (int o = 32; o > 0; o >>= 1) {
      pr += __shfl_down(pr, o); pw += __shfl_down(pw, o); pn += __shfl_down(pn, o);
    }
    if (lane == 0) {
      dr[(size_t)b * NN + n] = pr;
      dw[(size_t)b * NN + n] = pw;
      nrm[(size_t)b * NN + n] = pn;
    }
  }
}

// ---- addressing: cos->softmax->gate->shift->sharpen->normalize ----
__global__ __launch_bounds__(256) void addr_k(const float* __restrict__ dr,
                                              const float* __restrict__ dw,
                                              const float* __restrict__ nrm,
                                              const float* __restrict__ rpwp,
                                              float* rw, float* ww,
                                              float* __restrict__ ea,
                                              float* __restrict__ rvec) {
  __shared__ float wg[4096];
  __shared__ float s8[8];
  int head = blockIdx.x & 1, b = blockIdx.x >> 1;
  int tid = threadIdx.x;
  const float* p = rpwp + (size_t)b * 1036 + (head ? 262 : 0);
  const float* dot = (head ? dw : dr) + (size_t)b * NN;
  const float* n2 = nrm + (size_t)b * NN;
  float* wout = (head ? ww : rw) + (size_t)b * NN;

  float kv = p[tid];
  float kn = sqrtf(blk_sum(kv * kv, s8)) + EPS_;
  float beta = p[256], gate = p[257], sh0 = p[258], sh1 = p[259], sh2 = p[260], gamma = p[261];
  float spb = softplusf_(beta);
  float g = sigf(gate);
  float mx3 = fmaxf(sh0, fmaxf(sh1, sh2));
  float e0 = expf(sh0 - mx3), e1 = expf(sh1 - mx3), e2 = expf(sh2 - mx3);
  float esum = e0 + e1 + e2;
  float s0 = e0 / esum, s1 = e1 / esum, s2 = e2 / esum;
  float gp = 1.f + softplusf_(gamma);

  float l[16];
  float lmax = -1e30f;
#pragma unroll
  for (int i = 0; i < 16; ++i) {
    int n = tid + i * 256;
    float cs = dot[n] / ((sqrtf(n2[n]) + EPS_) * kn);
    l[i] = spb * cs;
    lmax = fmaxf(lmax, l[i]);
  }
  float Mx = blk_max(lmax, s8);
  float es = 0.f;
#pragma unroll
  for (int i = 0; i < 16; ++i) { l[i] = expf(l[i] - Mx); es += l[i]; }
  float SS = blk_sum(es, s8);
  float inv = 1.f / SS;
#pragma unroll
  for (int i = 0; i < 16; ++i) {
    int n = tid + i * 256;
    wg[n] = g * l[i] * inv + (1.f - g) * wout[n];
  }
  __syncthreads();
  float wt[16];
  float wsum = 0.f;
#pragma unroll
  for (int i = 0; i < 16; ++i) {
    int n = tid + i * 256;
    float sh = s0 * wg[(n + 1) & 4095] + s1 * wg[n] + s2 * wg[(n + 4095) & 4095];
    wt[i] = powf(sh + EPS_, gp);
    wsum += wt[i];
  }
  float WS = blk_sum(wsum, s8) + EPS_;
  float winv = 1.f / WS;
#pragma unroll
  for (int i = 0; i < 16; ++i) wout[tid + i * 256] = wt[i] * winv;

  if (head) {
    ea[(size_t)b * 512 + tid] = sigf(p[262 + tid]);
    ea[(size_t)b * 512 + 256 + tid] = tanhf(p[518 + tid]);
  } else {
    rvec[(size_t)b * 256 + tid] = 0.f;
  }
}

// ---- pass B: memory erase/add update + fused r = read_w_new . memory_new ----
template <int FIRST>
__global__ __launch_bounds__(256) void passB_k(float* mem, const float* __restrict__ ww,
                                               const float* __restrict__ rw,
                                               const float* __restrict__ ea,
                                               float* __restrict__ rvec) {
  __shared__ float eS[256], aS[256];
  __shared__ float rred[4][256];
  int b = blockIdx.y, tid = threadIdx.x;
  eS[tid] = ea[(size_t)b * 512 + tid];
  aS[tid] = ea[(size_t)b * 512 + 256 + tid];
  __syncthreads();
  int w = tid >> 6, lane = tid & 63;
  float4 e4 = *(float4*)&eS[lane * 4];
  float4 a4 = *(float4*)&aS[lane * 4];
  float4 racc = make_float4(0.f, 0.f, 0.f, 0.f);
  int n0 = blockIdx.x * 128 + w * 32;
  for (int rr = 0; rr < 32; ++rr) {
    int n = n0 + rr;
    float wt = ww[(size_t)b * NN + n];
    float rwv = rw[(size_t)b * NN + n];
    float4* row = (float4*)(mem + ((size_t)b * NN + n) * 256);
    float4 m;
    if (FIRST) {
      m.x = wt * a4.x; m.y = wt * a4.y; m.z = wt * a4.z; m.w = wt * a4.w;
    } else {
      m = row[lane];
      m.x = m.x * (1.f - wt * e4.x) + wt * a4.x;
      m.y = m.y * (1.f - wt * e4.y) + wt * a4.y;
      m.z = m.z * (1.f - wt * e4.z) + wt * a4.z;
      m.w = m.w * (1.f - wt * e4.w) + wt * a4.w;
    }
    row[lane] = m;
    racc.x += rwv * m.x; racc.y += rwv * m.y; racc.z += rwv * m.z; racc.w += rwv * m.w;
  }
  rred[w][lane * 4 + 0] = racc.x;
  rred[w][lane * 4 + 1] = racc.y;
  rred[w][lane * 4 + 2] = racc.z;
  rred[w][lane * 4 + 3] = racc.w;
  __syncthreads();
  float s = rred[0][tid] + rred[1][tid] + rred[2][tid] + rred[3][tid];
  atomicAdd(rvec + (size_t)b * 256 + tid, s);
}

extern "C" void kernel_launch(void* const* d_in, const int* in_sizes, int n_in,
                              void* d_out, int out_size, void* d_ws, size_t ws_size,
                              hipStream_t stream) {
  const int* tokens = (const int*)d_in[0];
  const float* emb_W = (const float*)d_in[1];
  const float* read_gate_W = (const float*)d_in[2];
  const float* read_gate_b = (const float*)d_in[3];
  const float* film_W = (const float*)d_in[4];
  const float* film_b = (const float*)d_in[5];
  const float* t_Wqkv = (const float*)d_in[6];
  const float* t_bqkv = (const float*)d_in[7];
  const float* t_Wo = (const float*)d_in[8];
  const float* t_bo = (const float*)d_in[9];
  const float* t_ln1_g = (const float*)d_in[10];
  const float* t_ln1_b = (const float*)d_in[11];
  const float* t_ln2_g = (const float*)d_in[12];
  const float* t_ln2_b = (const float*)d_in[13];
  const float* t_W1 = (const float*)d_in[14];
  const float* t_b1 = (const float*)d_in[15];
  const float* t_W2 = (const float*)d_in[16];
  const float* t_b2 = (const float*)d_in[17];
  const float* out_ln_g = (const float*)d_in[18];
  const float* out_ln_b = (const float*)d_in[19];
  const float* lstm_Wih = (const float*)d_in[20];
  const float* lstm_Whh = (const float*)d_in[21];
  const float* lstm_bih = (const float*)d_in[22];
  const float* lstm_bhh = (const float*)d_in[23];
  const float* head_W = (const float*)d_in[24];
  const float* head_b = (const float*)d_in[25];
  const float* read_W = (const float*)d_in[26];
  const float* read_b = (const float*)d_in[27];
  const float* write_W = (const float*)d_in[28];
  const float* write_b = (const float*)d_in[29];
  float* out = (float*)d_out;

  float* ws = (float*)d_ws;
  size_t off = 0;
  // ---- zero-initialized region (contiguous) ----
  float* read_w = ws + off; off += (size_t)BB * NN;
  float* write_w = ws + off; off += (size_t)BB * NN;
  float* record = ws + off; off += BB * DD;
  float* cx = ws + off; off += 2 * BB * DD;
  float* lstm_in = ws + off; off += 2 * BB * 512;
  float* r_vec = ws + off; off += BB * DD;
  float* dot_r = ws + off; off += (size_t)BB * NN;
  float* dot_w = ws + off; off += (size_t)BB * NN;
  float* norm2 = ws + off; off += (size_t)BB * NN;
  size_t zero_floats = off;
  // ---- not zeroed ----
  float* memory = ws + off; off += (size_t)BB * NN * DD;  // fully written by passB<1> at t=0
  float* hpe = ws + off; off += 9 * BB * DD;
  float* h = ws + off; off += 9 * BB * DD;
  float* qkv = ws + off; off += 9 * BB * 3 * DD;
  float* attnout = ws + off; off += 9 * BB * DD;
  float* attnl = ws + off; off += BB * DD;
  float* h2 = ws + off; off += BB * DD;
  float* mid = ws + off; off += 9 * BB * 4 * DD;
  float* mid32 = ws + off; off += BB * 4 * DD;
  float* c_out = ws + off; off += BB * DD;
  float* c_fin = ws + off; off += BB * DD;
  float* gates = ws + off; off += BB * 4 * DD;
  float* rpwp = ws + off; off += BB * 1036;
  float* ea = ws + off; off += BB * 2 * DD;
  float* Wc = ws + off; off += 2 * 1024 * 512;
  float* cb = ws + off; off += 2 * 1024;
  float* Wrw = ws + off; off += 1036 * 256;
  float* brw = ws + off; off += 1040;
  unsigned short* Wh = (unsigned short*)(ws + off); off += (size_t)VV * 256 / 2;
  unsigned short* cfb = (unsigned short*)(ws + off); off += BB * DD / 2;
  if (ws_size < off * sizeof(float)) return;

  (void)hipMemsetAsync(ws, 0, zero_floats * sizeof(float), stream);
  init_k<<<32, 256, 0, stream>>>(read_w, write_w, hpe);
  cvtw_k<<<(VV * 256 / 4 + 255) / 256, 256, 0, stream>>>(head_W, Wh, VV * 256 / 4);
  catlstm_k<<<4096, 256, 0, stream>>>(lstm_Wih, lstm_Whh, lstm_bih, lstm_bhh, Wc, cb);
  catrw_k<<<1036, 256, 0, stream>>>(read_W, read_b, write_W, write_b, Wrw, brw);

  auto gd = [](int n, int m, int tn, int tm) {
    return dim3((unsigned)((n + tn - 1) / tn), (unsigned)((m + tm - 1) / tm));
  };

  for (int t = 0; t < TT; ++t) {
    const int S = t + 2;
    const int M = S * BB;

    xin_k<<<BB, 256, 0, stream>>>(tokens, emb_W, read_gate_W, read_gate_b, film_W, film_b,
                                  record, r_vec, hpe, t);

    // ---- transformer layer 1 (all rows) ----
    {
      const int l = 0;
      gemm_k<32, 64, 0, 0, 1><<<gd(768, M, 64, 32), 256, 0, stream>>>(
          hpe, t_Wqkv + (size_t)l * 768 * 256, t_bqkv + l * 768, nullptr,
          t_ln1_g + l * 256, t_ln1_b + l * 256, qkv, M, 768, 256);
      attn_k<<<BB * HH, 128, 0, stream>>>(qkv, attnout, S);
      gemm_k<32, 32, 0, 1, 0><<<gd(256, M, 32, 32), 256, 0, stream>>>(
          attnout, t_Wo + (size_t)l * 256 * 256, t_bo + l * 256, hpe, nullptr, nullptr, h, M, 256, 256);
      gemm_k<32, 64, 1, 0, 1><<<gd(1024, M, 64, 32), 256, 0, stream>>>(
          h, t_W1 + (size_t)l * 1024 * 256, t_b1 + l * 1024, nullptr,
          t_ln2_g + l * 256, t_ln2_b + l * 256, mid, M, 1024, 256);
      gemm_k<32, 32, 0, 1, 0><<<gd(256, M, 32, 32), 256, 0, stream>>>(
          mid, t_W2 + (size_t)l * 256 * 1024, t_b2 + l * 256, h, nullptr, nullptr, h, M, 256, 1024);
    }
    // ---- transformer layer 2 (k/v all rows; proj/ffn last row only) ----
    {
      const int l = 1;
      gemm_k<32, 64, 0, 0, 1><<<gd(768, M, 64, 32), 256, 0, stream>>>(
          h, t_Wqkv + (size_t)l * 768 * 256, t_bqkv + l * 768, nullptr,
          t_ln1_g + l * 256, t_ln1_b + l * 256, qkv, M, 768, 256);
      attnl_k<<<BB * HH, 64, 0, stream>>>(qkv, attnl, S);
      const float* hlast = h + (size_t)(S - 1) * BB * DD;
      gemm_k<32, 32, 0, 1, 0><<<gd(256, BB, 32, 32), 256, 0, stream>>>(
          attnl, t_Wo + (size_t)l * 256 * 256, t_bo + l * 256, hlast, nullptr, nullptr, h2, BB, 256, 256);
      gemm_k<32, 64, 1, 0, 1><<<gd(1024, BB, 64, 32), 256, 0, stream>>>(
          h2, t_W1 + (size_t)l * 1024 * 256, t_b1 + l * 1024, nullptr,
          t_ln2_g + l * 256, t_ln2_b + l * 256, mid32, BB, 1024, 256);
      gemm_k<32, 32, 0, 1, 0><<<gd(256, BB, 32, 32), 256, 0, stream>>>(
          mid32, t_W2 + (size_t)l * 256 * 1024, t_b2 + l * 256, h2, nullptr, nullptr, h2, BB, 256, 1024);
    }

    ln_k<<<BB, 256, 0, stream>>>(h2, out_ln_g, out_ln_b, c_out, lstm_in);

    // ---- LSTM (2 layers, fused Wih|Whh gemm) ----
    for (int l = 0; l < 2; ++l) {
      gemm_k<32, 64, 0, 0, 0><<<gd(1024, BB, 64, 32), 256, 0, stream>>>(
          lstm_in + (size_t)l * BB * 512, Wc + (size_t)l * 1024 * 512, cb + l * 1024,
          nullptr, nullptr, nullptr, gates, BB, 1024, 512);
      lstmpw_k<<<BB, 256, 0, stream>>>(gates, cx + (size_t)l * BB * DD,
                                       lstm_in + (size_t)l * BB * 512,
                                       lstm_in + (size_t)(l + 1 < 2 ? l + 1 : 0) * BB * 512,
                                       c_out, c_fin, cfb, record, l == 1);
    }

    head_k<<<(VV + 63) / 64, 256, 0, stream>>>(Wh, cfb, head_b, out + (size_t)t * BB * VV);

    if (t < TT - 1) {
      gemm_k<32, 64, 0, 0, 0><<<gd(1036, BB, 64, 32), 256, 0, stream>>>(
          c_fin, Wrw, brw, nullptr, nullptr, nullptr, rpwp, BB, 1036, 256);
      if (t > 0)
        passA_k<<<dim3(NN / 16, BB), 256, 0, stream>>>(memory, rpwp, dot_r, dot_w, norm2);
      addr_k<<<2 * BB, 256, 0, stream>>>(dot_r, dot_w, norm2, rpwp, read_w, write_w, ea, r_vec);
      if (t == 0)
        passB_k<1><<<dim3(NN / 128, BB), 256, 0, stream>>>(memory, write_w, read_w, ea, r_vec);
      else
        passB_k<0><<<dim3(NN / 128, BB), 256, 0, stream>>>(memory, write_w, read_w, ea, r_vec);
    }
  }
}